// Round 1
// baseline (523.363 us; speedup 1.0000x reference)
//
#include <hip/hip_runtime.h>

// SMINSparseMeanPool: x (B,D,N=64) f32 -> out (B,D,C=4,N,N) f32
// out[b,d,c,s,e] = mask(s,e) * (P[EE]-P[SS]) / (EE-SS)
// where P is the zero-prefixed cumsum of x[b,d,:],
//   L = e+1-s;  L<4 ? (SS=s, EE=e+1) : (SS=s+(c*L>>2), EE=s+((c+1)*L>>2)); EE=max(EE,SS+1)
// mask(s,e): d=e-s >= 0 and ( d<=15  |  (17<=d<=31 & d odd & s even)  |  (d>=35 & d%4==3 & s%4==0) )

#define NN 64
#define COUT 4

__global__ __launch_bounds__(256)
void smin_pool_kernel(const float* __restrict__ x, float* __restrict__ out) {
    __shared__ float P[NN + 1];

    const int bd = blockIdx.x;
    const int t  = threadIdx.x;

    // ---- wave-0: load 64 inputs, inclusive shuffle-scan, store prefix to LDS ----
    if (t < 64) {
        float v = x[(size_t)bd * NN + t];
        #pragma unroll
        for (int off = 1; off < 64; off <<= 1) {
            float u = __shfl_up(v, off, 64);
            if (t >= off) v += u;
        }
        P[t + 1] = v;
        if (t == 0) P[0] = 0.0f;
    }
    __syncthreads();

    // ---- emit 4*64*64 = 16384 floats = 4096 float4 per block ----
    float4* out4 = (float4*)(out + (size_t)bd * (COUT * NN * NN));

    #pragma unroll
    for (int k = 0; k < 16; ++k) {
        const int idx4 = t + k * 256;          // [0, 4096)
        const int c  = idx4 >> 10;             // [0,4)
        const int s  = (idx4 >> 4) & 63;       // [0,64)
        const int e0 = (idx4 & 15) << 2;       // e base, [0,64) step 4

        float4 r;
        float* rp = &r.x;
        #pragma unroll
        for (int j = 0; j < 4; ++j) {
            const int e = e0 + j;
            const int d = e - s;
            bool m;
            if (d < 0)        m = false;
            else if (d <= 15) m = true;                       // stride-1 band (incl diagonal)
            else if (d <= 31) m = (d & 1) && !(s & 1);        // stride-2: odd offsets 17..31, s even
            else              m = ((d & 3) == 3) && !(s & 3); // stride-4: offsets 35,39,..,63, s%4==0

            float val = 0.0f;
            if (m) {
                const int L = d + 1;
                int ss, ee;
                if (L < COUT) { ss = s; ee = e + 1; }
                else {
                    ss = s + ((c * L) >> 2);
                    ee = s + (((c + 1) * L) >> 2);
                }
                if (ee < ss + 1) ee = ss + 1;
                val = (P[ee] - P[ss]) / (float)(ee - ss);
            }
            rp[j] = val;
        }
        out4[idx4] = r;
    }
}

extern "C" void kernel_launch(void* const* d_in, const int* in_sizes, int n_in,
                              void* d_out, int out_size, void* d_ws, size_t ws_size,
                              hipStream_t stream) {
    const float* x = (const float*)d_in[0];
    float* out = (float*)d_out;
    const int BD = in_sizes[0] / NN;   // 16*512 = 8192 rows
    smin_pool_kernel<<<BD, 256, 0, stream>>>(x, out);
}